// Round 1
// baseline (840.211 us; speedup 1.0000x reference)
//
#include <hip/hip_runtime.h>
#include <hip/hip_bf16.h>

// Sparse 3^3 conv x2 + LayerNorm + ReLU + residual. N=400000, C=32, K=27.
// Contract: ALL float inputs are FLOAT32, output f32, nbr int32.
// Workspace: h (bf16, 25.6MB) at d_ws+0; xb (bf16 copy of x, 25.6MB) at
// d_ws+25.6MB when ws_size allows (else f32-gather fallback for pass 1).
//
// Round-10 restructure (latency-bound per rocprof: MfmaUtil 2.5 / VALU 16.7 /
// HBM 6.4 / occ 33 -- nothing busy, waves waiting on nb->ballot->gather chain):
//  * preload all 26 non-center neighbor indices per tile (one latency, not 26)
//  * nbr[13] == identity by construction: never loaded; center B-frag in regs,
//    center gather coalesced. LDS 55296 -> 53248 (3 blocks/CU possible).
//  * branch-free D-deep pipelined exec-masked gathers (D=8 bf16 / D=4 f32)
//  * x pre-converted to bf16 so both passes gather 16B/lane
//  * nontemporal nbr loads + out stores (protect L2 for feature rows)

#define NV   400000

typedef __bf16 bf16x8 __attribute__((ext_vector_type(8)));
typedef float  f32x4  __attribute__((ext_vector_type(4)));

union ABu { bf16x8 v; int4 i4; unsigned short us[8]; };

__device__ __forceinline__ unsigned short rb_f2bf(float f) {
    unsigned int u = __float_as_uint(f);
    return (unsigned short)((u + 0x7fffu + ((u >> 16) & 1u)) >> 16);
}

// x (f32) -> bf16, 8 elems/thread. Exact grid: NV*32/8 = 1.6M threads.
__global__ __launch_bounds__(512) void xcvt_kernel(const float* __restrict__ xf,
                                                   unsigned short* __restrict__ xb)
{
    size_t i = ((size_t)blockIdx.x * 512 + threadIdx.x) * 8;
    float4 p0 = *(const float4*)(xf + i);
    float4 p1 = *(const float4*)(xf + i + 4);
    ABu a;
    a.us[0] = rb_f2bf(p0.x); a.us[1] = rb_f2bf(p0.y);
    a.us[2] = rb_f2bf(p0.z); a.us[3] = rb_f2bf(p0.w);
    a.us[4] = rb_f2bf(p1.x); a.us[5] = rb_f2bf(p1.y);
    a.us[6] = rb_f2bf(p1.z); a.us[7] = rb_f2bf(p1.w);
    *(int4*)(xb + i) = a.i4;
}

// WRITE_OUT=false: h(bf16) = relu(LN(conv(gather)))     (pass 1)
// WRITE_OUT=true : out(f32) = relu(LN(conv(gather)) + x) (pass 2)
// SRC_F32=true   : gather f32 rows from xf (fallback, no xb workspace)
// SRC_F32=false  : gather bf16 rows from gsrc (xb for pass 1, hbuf for pass 2)
template <bool WRITE_OUT, bool SRC_F32>
__global__ __launch_bounds__(512, 4) void ResidualBlock_37452114821416_kernel(
    const float* __restrict__ xf,     // x [NV,32] f32 (f32 gather src / residual)
    const int*   __restrict__ nbr,    // [27,NV]
    const float* __restrict__ Wf,     // [27,32,32] f32
    const float* __restrict__ gf,     // [32]
    const float* __restrict__ bfv,    // [32]
    float*       __restrict__ outf,   // [NV,32] f32
    unsigned short* __restrict__ hbuf,// [NV,32] bf16 scratch (pass-1 dst)
    const unsigned short* __restrict__ gsrc)  // bf16 gather source
{
    // Per-lane MFMA B-fragments for the 26 NON-center offsets, packed bf16:
    // Bp[kk*1024 + f*512 + lane*8 + j] = W[k][ci=(lane>>4)*8+j][co=(lane&15)+16f]
    // with k = kk + (kk>=13). 53248 B.
    __shared__ __align__(16) unsigned short Bp[26 * 1024];
    for (int e = threadIdx.x; e < 26 * 1024; e += 512) {
        int kk   = e >> 10;
        int k    = kk + (kk >= 13 ? 1 : 0);
        int r    = e & 1023;
        int f    = r >> 9;
        int lane = (r >> 3) & 63;
        int j    = r & 7;
        int ci   = ((lane >> 4) << 3) + j;
        int co   = (lane & 15) + (f << 4);
        Bp[e] = rb_f2bf(Wf[k * 1024 + ci * 32 + co]);
    }

    const int lane = threadIdx.x & 63;
    const int wv   = threadIdx.x >> 6;
    const int q    = lane >> 4, n = lane & 15;
    const int i0   = blockIdx.x * 512 + wv * 64;   // 64 voxels per wave

    // center-offset (k=13) B fragments live in registers
    ABu cb0, cb1;
    #pragma unroll
    for (int j = 0; j < 8; ++j) {
        int ci = (q << 3) + j;
        cb0.us[j] = rb_f2bf(Wf[13 * 1024 + ci * 32 + n]);
        cb1.us[j] = rb_f2bf(Wf[13 * 1024 + ci * 32 + n + 16]);
    }
    __syncthreads();

    const float gv0 = gf[n],  gv1 = gf[n + 16];
    const float bv0 = bfv[n], bv1 = bfv[n + 16];

    constexpr int D = SRC_F32 ? 4 : 8;   // gather pipeline depth

    #pragma unroll 1
    for (int t = 0; t < 4; ++t) {
        const int  v  = i0 + t * 16 + n;           // A-row m = lane&15
        const bool ok = (v < NV);

        // ---- preload all 26 neighbor indices: issued together, one latency ----
        int jn[26];
        #pragma unroll
        for (int kk = 0; kk < 26; ++kk) {
            const int k = kk + (kk >= 13 ? 1 : 0);
            int jv = -1;
            if (ok) jv = __builtin_nontemporal_load(nbr + (size_t)k * NV + v);
            jn[kk] = jv;
        }

        // ---- center contribution: jn == v, coalesced self-row gather ----
        ABu ac; ac.i4 = make_int4(0, 0, 0, 0);
        if (ok) {
            if constexpr (SRC_F32) {
                const float* src = xf + (size_t)v * 32 + q * 8;
                float4 p0 = *(const float4*)(src);
                float4 p1 = *(const float4*)(src + 4);
                ac.us[0] = rb_f2bf(p0.x); ac.us[1] = rb_f2bf(p0.y);
                ac.us[2] = rb_f2bf(p0.z); ac.us[3] = rb_f2bf(p0.w);
                ac.us[4] = rb_f2bf(p1.x); ac.us[5] = rb_f2bf(p1.y);
                ac.us[6] = rb_f2bf(p1.z); ac.us[7] = rb_f2bf(p1.w);
            } else {
                ac.i4 = *(const int4*)(gsrc + (size_t)v * 32 + q * 8);
            }
        }
        f32x4 acc0 = (f32x4){0.f, 0.f, 0.f, 0.f};
        f32x4 acc1 = (f32x4){0.f, 0.f, 0.f, 0.f};
        acc0 = __builtin_amdgcn_mfma_f32_16x16x32_bf16(ac.v, cb0.v, acc0, 0, 0, 0);
        acc1 = __builtin_amdgcn_mfma_f32_16x16x32_bf16(ac.v, cb1.v, acc1, 0, 0, 0);

        // ---- D-deep software-pipelined exec-masked gathers over 26 offsets ----
        if constexpr (!SRC_F32) {
            int4 pb[D];
            #pragma unroll
            for (int kk = 0; kk < D; ++kk) {
                int j = jn[kk];
                pb[kk] = make_int4(0, 0, 0, 0);
                if (j >= 0) pb[kk] = *(const int4*)(gsrc + (size_t)j * 32 + q * 8);
            }
            #pragma unroll
            for (int kk = 0; kk < 26; ++kk) {
                ABu b0, b1, a;
                b0.i4 = *(const int4*)(Bp + kk * 1024 + lane * 8);
                b1.i4 = *(const int4*)(Bp + kk * 1024 + 512 + lane * 8);
                a.i4  = pb[kk % D];                       // consume slot (vmcnt wait)
                if (kk + D < 26) {                        // refill same slot
                    int j = jn[kk + D];
                    pb[kk % D] = make_int4(0, 0, 0, 0);
                    if (j >= 0) pb[kk % D] = *(const int4*)(gsrc + (size_t)j * 32 + q * 8);
                }
                acc0 = __builtin_amdgcn_mfma_f32_16x16x32_bf16(a.v, b0.v, acc0, 0, 0, 0);
                acc1 = __builtin_amdgcn_mfma_f32_16x16x32_bf16(a.v, b1.v, acc1, 0, 0, 0);
            }
        } else {
            float4 pf[D][2];
            #pragma unroll
            for (int kk = 0; kk < D; ++kk) {
                int j = jn[kk];
                if (j >= 0) {
                    const float* src = xf + (size_t)j * 32 + q * 8;
                    pf[kk][0] = *(const float4*)(src);
                    pf[kk][1] = *(const float4*)(src + 4);
                }
            }
            #pragma unroll
            for (int kk = 0; kk < 26; ++kk) {
                ABu b0, b1, a;
                b0.i4 = *(const int4*)(Bp + kk * 1024 + lane * 8);
                b1.i4 = *(const int4*)(Bp + kk * 1024 + 512 + lane * 8);
                float4 p0 = pf[kk % D][0];
                float4 p1 = pf[kk % D][1];
                if (kk + D < 26) {
                    int j = jn[kk + D];
                    if (j >= 0) {
                        const float* src = xf + (size_t)j * 32 + q * 8;
                        pf[kk % D][0] = *(const float4*)(src);
                        pf[kk % D][1] = *(const float4*)(src + 4);
                    }
                }
                if (jn[kk] >= 0) {                        // predicated convert
                    a.us[0] = rb_f2bf(p0.x); a.us[1] = rb_f2bf(p0.y);
                    a.us[2] = rb_f2bf(p0.z); a.us[3] = rb_f2bf(p0.w);
                    a.us[4] = rb_f2bf(p1.x); a.us[5] = rb_f2bf(p1.y);
                    a.us[6] = rb_f2bf(p1.z); a.us[7] = rb_f2bf(p1.w);
                } else {
                    a.i4 = make_int4(0, 0, 0, 0);
                }
                acc0 = __builtin_amdgcn_mfma_f32_16x16x32_bf16(a.v, b0.v, acc0, 0, 0, 0);
                acc1 = __builtin_amdgcn_mfma_f32_16x16x32_bf16(a.v, b1.v, acc1, 0, 0, 0);
            }
        }

        // ---- epilogue for this 16-voxel tile. C/D: cout = lane&15 (+16 frag1),
        // voxel row = q*4 + r. LN reduce over the 16-lane n-group. ----
        #pragma unroll
        for (int r = 0; r < 4; ++r) {
            float x0 = acc0[r], x1 = acc1[r];
            float s  = x0 + x1;
            float ss = x0 * x0 + x1 * x1;
            #pragma unroll
            for (int mm = 1; mm <= 8; mm <<= 1) {
                s  += __shfl_xor(s, mm);
                ss += __shfl_xor(ss, mm);
            }
            float mu  = s * (1.f / 32.f);
            float var = ss * (1.f / 32.f) - mu * mu;
            float rs  = rsqrtf(var + 1e-6f);
            int vv = i0 + t * 16 + q * 4 + r;
            if (vv < NV) {
                float y0 = (x0 - mu) * rs * gv0 + bv0;
                float y1 = (x1 - mu) * rs * gv1 + bv1;
                if constexpr (WRITE_OUT) {
                    y0 += xf[(size_t)vv * 32 + n];
                    y1 += xf[(size_t)vv * 32 + n + 16];
                    __builtin_nontemporal_store(fmaxf(y0, 0.f), outf + (size_t)vv * 32 + n);
                    __builtin_nontemporal_store(fmaxf(y1, 0.f), outf + (size_t)vv * 32 + n + 16);
                } else {
                    hbuf[(size_t)vv * 32 + n]      = rb_f2bf(fmaxf(y0, 0.f));
                    hbuf[(size_t)vv * 32 + n + 16] = rb_f2bf(fmaxf(y1, 0.f));
                }
            }
        }
    }
}

extern "C" void kernel_launch(void* const* d_in, const int* in_sizes, int n_in,
                              void* d_out, int out_size, void* d_ws, size_t ws_size,
                              hipStream_t stream)
{
    // setup_inputs() dict order: x, nbr, W1, g1, b1, W2, g2, b2 — all f32 except nbr
    const float* x   = (const float*)d_in[0];
    const int*   nbr = (const int*)d_in[1];
    const float* W1  = (const float*)d_in[2];
    const float* g1  = (const float*)d_in[3];
    const float* b1  = (const float*)d_in[4];
    const float* W2  = (const float*)d_in[5];
    const float* g2  = (const float*)d_in[6];
    const float* b2  = (const float*)d_in[7];
    float* out = (float*)d_out;

    unsigned short* h  = (unsigned short*)d_ws;              // 25.6 MB (proven)
    unsigned short* xb = h + (size_t)NV * 32;                // +25.6 MB
    const bool have_xb = ws_size >= (size_t)NV * 32 * 2 * 2; // 51.2 MB needed

    const int nblk = (NV + 511) / 512;   // 782 blocks x 8 waves x 64 voxels

    if (have_xb) {
        // pass 0: xb = bf16(x)  (NV*32/8/512 = 3125 blocks, exact)
        xcvt_kernel<<<3125, 512, 0, stream>>>(x, xb);
        // pass 1: h = relu(LN(conv1(xb)))   bf16 gather, D=8 pipeline
        ResidualBlock_37452114821416_kernel<false, false><<<nblk, 512, 0, stream>>>(
            x, nbr, W1, g1, b1, out, h, xb);
    } else {
        // fallback: f32 gather, D=4 pipeline
        ResidualBlock_37452114821416_kernel<false, true><<<nblk, 512, 0, stream>>>(
            x, nbr, W1, g1, b1, out, h, (const unsigned short*)0);
    }
    // pass 2: out = relu(LN(conv2(h)) + x)  bf16 gather from h
    ResidualBlock_37452114821416_kernel<true, false><<<nblk, 512, 0, stream>>>(
        x, nbr, W2, g2, b2, out, h, h);

    (void)in_sizes; (void)n_in; (void)out_size;
}

// Round 2
// 276.871 us; speedup vs baseline: 3.0347x; 3.0347x over previous
//
#include <hip/hip_runtime.h>
#include <hip/hip_bf16.h>

// Sparse 3^3 conv x2 + LayerNorm + ReLU + residual. N=400000, C=32, K=27.
// Contract: ALL float inputs are FLOAT32, output f32, nbr int32.
// Workspace: h (bf16, 25.6MB) at d_ws+0; xb (bf16 copy of x) at +25.6MB.
//
// Round-2 design (post-mortem of round 1: voxel-outer order destroyed L2 reuse
// -- FETCH 81->675MB -- and jn[26]/pb[D] arrays spilled to scratch, VGPR=64
// reported with >100 live values, +300MB scratch write / +600MB fetch):
//  * k-OUTER loop restored (L2 window ~2MB per XCD << 4MB -> rows reused 27x)
//  * NO runtime-indexed arrays: two named 4-slot gather buffers (gA/gB),
//    fully unrolled 13-pair pipeline, indices prefetched 2 offsets ahead
//  * one coalesced per-wave index load per offset + __shfl distribution
//    (replaces 4 broadcast loads per offset)
//  * identity-center offset: no index load, coalesced self-gather, B-frag in
//    registers; LDS 53248B -> 3 blocks/CU by LDS
//  * bf16 pre-convert of x (xcvt) so both passes gather 16B/lane
//  * nontemporal ONLY on streamed nbr index loads; regular stores everywhere

#define NV 400000

typedef __bf16 bf16x8 __attribute__((ext_vector_type(8)));
typedef float  f32x4  __attribute__((ext_vector_type(4)));

union ABu { bf16x8 v; int4 i4; unsigned short us[8]; };

__device__ __forceinline__ unsigned short rb_f2bf(float f) {
    unsigned int u = __float_as_uint(f);
    return (unsigned short)((u + 0x7fffu + ((u >> 16) & 1u)) >> 16);
}

// k index for the 26 non-center offsets (skips k=13, the identity offset)
#define KIDX(kk) ((kk) + ((kk) >= 13 ? 1 : 0))

#define MFMA_BF16 __builtin_amdgcn_mfma_f32_16x16x32_bf16

// x (f32) -> bf16, 8 elems/thread. Exact grid: NV*32/8/512 = 3125 blocks.
__global__ __launch_bounds__(512) void xcvt_kernel(const float* __restrict__ xf,
                                                   unsigned short* __restrict__ xb)
{
    size_t i = ((size_t)blockIdx.x * 512 + threadIdx.x) * 8;
    float4 p0 = *(const float4*)(xf + i);
    float4 p1 = *(const float4*)(xf + i + 4);
    ABu a;
    a.us[0] = rb_f2bf(p0.x); a.us[1] = rb_f2bf(p0.y);
    a.us[2] = rb_f2bf(p0.z); a.us[3] = rb_f2bf(p0.w);
    a.us[4] = rb_f2bf(p1.x); a.us[5] = rb_f2bf(p1.y);
    a.us[6] = rb_f2bf(p1.z); a.us[7] = rb_f2bf(p1.w);
    *(int4*)(xb + i) = a.i4;
}

// Gather the 4 tile-slots for one offset from a wave-wide index register.
// jall lane l holds nbr index of voxel i0+l; tile t row n needs lane t*16+n.
#define GATHER4(gbuf, jall)                                                   \
    do {                                                                      \
        _Pragma("unroll")                                                     \
        for (int _t = 0; _t < 4; ++_t) {                                      \
            int _j = __shfl((jall), _t * 16 + n);                             \
            gbuf[_t] = make_int4(0, 0, 0, 0);                                 \
            if (_j >= 0)                                                      \
                gbuf[_t] = *(const int4*)(gsrc + ((size_t)_j << 5) + qo);     \
        }                                                                     \
    } while (0)

// Consume one offset's gather buffer: 2 LDS B-frag reads + 8 MFMAs.
#define CONSUME(kk, gbuf)                                                     \
    do {                                                                      \
        ABu _b0, _b1;                                                         \
        _b0.i4 = *(const int4*)(Bp + (kk) * 1024 + lane * 8);                 \
        _b1.i4 = *(const int4*)(Bp + (kk) * 1024 + 512 + lane * 8);           \
        _Pragma("unroll")                                                     \
        for (int _t = 0; _t < 4; ++_t) {                                      \
            ABu _a; _a.i4 = gbuf[_t];                                         \
            acc[_t][0] = MFMA_BF16(_a.v, _b0.v, acc[_t][0], 0, 0, 0);         \
            acc[_t][1] = MFMA_BF16(_a.v, _b1.v, acc[_t][1], 0, 0, 0);         \
        }                                                                     \
    } while (0)

// WRITE_OUT=false: h(bf16) = relu(LN(conv(gsrc)))      (pass 1, gsrc=xb)
// WRITE_OUT=true : out(f32) = relu(LN(conv(gsrc)) + x) (pass 2, gsrc=h)
template <bool WRITE_OUT>
__global__ __launch_bounds__(512, 4) void ResidualBlock_37452114821416_kernel(
    const float* __restrict__ xf,     // x [NV,32] f32 (residual, pass 2)
    const int*   __restrict__ nbr,    // [27,NV]
    const float* __restrict__ Wf,     // [27,32,32] f32
    const float* __restrict__ gf,     // [32]
    const float* __restrict__ bfv,    // [32]
    float*       __restrict__ outf,   // [NV,32] f32
    unsigned short* __restrict__ hbuf,// [NV,32] bf16 scratch (pass-1 dst)
    const unsigned short* __restrict__ gsrc)  // bf16 gather source
{
    // Per-lane MFMA B-fragments for the 26 non-center offsets, packed bf16:
    // Bp[kk*1024 + f*512 + lane*8 + j] = W[k][ci=(lane>>4)*8+j][co=(lane&15)+16f]
    __shared__ __align__(16) unsigned short Bp[26 * 1024];
    for (int e = threadIdx.x; e < 26 * 1024; e += 512) {
        int kk = e >> 10;
        int k  = KIDX(kk);
        int r  = e & 1023;
        int f  = r >> 9;
        int ll = (r >> 3) & 63;
        int j  = r & 7;
        int ci = ((ll >> 4) << 3) + j;
        int co = (ll & 15) + (f << 4);
        Bp[e] = rb_f2bf(Wf[k * 1024 + ci * 32 + co]);
    }

    const int  lane = threadIdx.x & 63;
    const int  wv   = threadIdx.x >> 6;
    const int  q    = lane >> 4, n = lane & 15;
    const int  i0   = blockIdx.x * 512 + wv * 64;   // 64 voxels per wave
    const int  v64  = i0 + lane;
    const bool okv  = v64 < NV;
    const int  qo   = q * 8;                        // bf16-element offset in row

    // center-offset (k=13, identity map) B fragments live in registers
    ABu cb0, cb1;
    #pragma unroll
    for (int j = 0; j < 8; ++j) {
        int ci = (q << 3) + j;
        cb0.us[j] = rb_f2bf(Wf[13 * 1024 + ci * 32 + n]);
        cb1.us[j] = rb_f2bf(Wf[13 * 1024 + ci * 32 + n + 16]);
    }
    __syncthreads();

    f32x4 acc[4][2];
    #pragma unroll
    for (int t = 0; t < 4; ++t) {
        acc[t][0] = (f32x4){0.f, 0.f, 0.f, 0.f};
        acc[t][1] = (f32x4){0.f, 0.f, 0.f, 0.f};
    }

    // ---- prologue: indices for kk=0,1; center rows; gathers kk=0,1; idx kk=2,3
    int jA = okv ? __builtin_nontemporal_load(nbr + (size_t)KIDX(0) * NV + v64) : -1;
    int jB = okv ? __builtin_nontemporal_load(nbr + (size_t)KIDX(1) * NV + v64) : -1;

    int4 cgb[4];                       // center self-rows (coalesced)
    #pragma unroll
    for (int t = 0; t < 4; ++t) {
        int vt = i0 + t * 16 + n;
        cgb[t] = make_int4(0, 0, 0, 0);
        if (vt < NV) cgb[t] = *(const int4*)(gsrc + ((size_t)vt << 5) + qo);
    }

    int4 gA[4], gB[4];
    GATHER4(gA, jA);                   // kk=0
    GATHER4(gB, jB);                   // kk=1

    int jE = okv ? __builtin_nontemporal_load(nbr + (size_t)KIDX(2) * NV + v64) : -1;
    int jO = okv ? __builtin_nontemporal_load(nbr + (size_t)KIDX(3) * NV + v64) : -1;

    // center MFMA (consumes cgb, frees those regs for the loop)
    #pragma unroll
    for (int t = 0; t < 4; ++t) {
        ABu a; a.i4 = cgb[t];
        acc[t][0] = MFMA_BF16(a.v, cb0.v, acc[t][0], 0, 0, 0);
        acc[t][1] = MFMA_BF16(a.v, cb1.v, acc[t][1], 0, 0, 0);
    }

    // ---- main pipeline: 13 fully-unrolled pairs (kk = 2p, 2p+1).
    // Invariant at pair p: gA holds kk=2p, gB holds kk=2p+1 (in flight),
    // jE holds indices for kk=2p+2, jO for kk=2p+3 (in flight).
    #pragma unroll
    for (int p = 0; p < 13; ++p) {
        int jE2 = -1, jO2 = -1;
        if (2 * p + 4 < 26 && okv)
            jE2 = __builtin_nontemporal_load(nbr + (size_t)KIDX(2 * p + 4) * NV + v64);
        if (2 * p + 5 < 26 && okv)
            jO2 = __builtin_nontemporal_load(nbr + (size_t)KIDX(2 * p + 5) * NV + v64);

        CONSUME(2 * p, gA);
        if (2 * p + 2 < 26) GATHER4(gA, jE);   // refill for kk=2p+2

        CONSUME(2 * p + 1, gB);
        if (2 * p + 3 < 26) GATHER4(gB, jO);   // refill for kk=2p+3

        jE = jE2; jO = jO2;
    }

    // ---- epilogue. C/D layout: cout = lane&15 (+16 frag1), voxel row = q*4+r.
    const float gv0 = gf[n],  gv1 = gf[n + 16];
    const float bv0 = bfv[n], bv1 = bfv[n + 16];
    #pragma unroll
    for (int t = 0; t < 4; ++t) {
        #pragma unroll
        for (int r = 0; r < 4; ++r) {
            float x0 = acc[t][0][r], x1 = acc[t][1][r];
            float s  = x0 + x1;
            float ss = x0 * x0 + x1 * x1;
            #pragma unroll
            for (int mm = 1; mm <= 8; mm <<= 1) {   // LN reduce over 16-lane n-group
                s  += __shfl_xor(s, mm);
                ss += __shfl_xor(ss, mm);
            }
            float mu  = s * (1.f / 32.f);
            float var = ss * (1.f / 32.f) - mu * mu;
            float rs  = rsqrtf(var + 1e-6f);
            int vv = i0 + t * 16 + q * 4 + r;
            if (vv < NV) {
                float y0 = (x0 - mu) * rs * gv0 + bv0;
                float y1 = (x1 - mu) * rs * gv1 + bv1;
                if constexpr (WRITE_OUT) {
                    y0 += xf[(size_t)vv * 32 + n];
                    y1 += xf[(size_t)vv * 32 + n + 16];
                    outf[(size_t)vv * 32 + n]      = fmaxf(y0, 0.f);
                    outf[(size_t)vv * 32 + n + 16] = fmaxf(y1, 0.f);
                } else {
                    hbuf[(size_t)vv * 32 + n]      = rb_f2bf(fmaxf(y0, 0.f));
                    hbuf[(size_t)vv * 32 + n + 16] = rb_f2bf(fmaxf(y1, 0.f));
                }
            }
        }
    }
}

// Fallback pass-1 (no workspace room for xb): round-0-proven serial structure,
// f32 gathers straight from x. Only used when ws_size < 51.2MB.
__global__ __launch_bounds__(512, 4) void pass1_f32_kernel(
    const float* __restrict__ xf, const int* __restrict__ nbr,
    const float* __restrict__ Wf, const float* __restrict__ gf,
    const float* __restrict__ bfv, unsigned short* __restrict__ hbuf)
{
    __shared__ __align__(16) unsigned short Bp[27 * 1024];
    for (int e = threadIdx.x; e < 27 * 1024; e += 512) {
        int k = e >> 10, r = e & 1023, f = r >> 9;
        int ll = (r >> 3) & 63, j = r & 7;
        int ci = ((ll >> 4) << 3) + j, co = (ll & 15) + (f << 4);
        Bp[e] = rb_f2bf(Wf[k * 1024 + ci * 32 + co]);
    }
    __syncthreads();
    const int lane = threadIdx.x & 63, wv = threadIdx.x >> 6;
    const int q = lane >> 4, n = lane & 15;
    const int i0 = blockIdx.x * 512 + wv * 64;
    f32x4 acc[4][2];
    #pragma unroll
    for (int t = 0; t < 4; ++t) { acc[t][0] = (f32x4){0,0,0,0}; acc[t][1] = (f32x4){0,0,0,0}; }
    for (int k = 0; k < 27; ++k) {
        ABu b0, b1;
        b0.i4 = *(const int4*)(Bp + k * 1024 + lane * 8);
        b1.i4 = *(const int4*)(Bp + k * 1024 + 512 + lane * 8);
        const int* nb = nbr + (size_t)k * NV;
        #pragma unroll
        for (int t = 0; t < 4; ++t) {
            int v = i0 + t * 16 + n;
            int jn = (v < NV) ? nb[v] : -1;
            if (__ballot(jn >= 0) == 0ull) continue;
            ABu a; a.i4 = make_int4(0, 0, 0, 0);
            if (jn >= 0) {
                const float* src = xf + (size_t)jn * 32 + q * 8;
                float4 p0 = *(const float4*)(src);
                float4 p1 = *(const float4*)(src + 4);
                a.us[0] = rb_f2bf(p0.x); a.us[1] = rb_f2bf(p0.y);
                a.us[2] = rb_f2bf(p0.z); a.us[3] = rb_f2bf(p0.w);
                a.us[4] = rb_f2bf(p1.x); a.us[5] = rb_f2bf(p1.y);
                a.us[6] = rb_f2bf(p1.z); a.us[7] = rb_f2bf(p1.w);
            }
            acc[t][0] = MFMA_BF16(a.v, b0.v, acc[t][0], 0, 0, 0);
            acc[t][1] = MFMA_BF16(a.v, b1.v, acc[t][1], 0, 0, 0);
        }
    }
    const float gv0 = gf[n], gv1 = gf[n + 16];
    const float bv0 = bfv[n], bv1 = bfv[n + 16];
    #pragma unroll
    for (int t = 0; t < 4; ++t) {
        #pragma unroll
        for (int r = 0; r < 4; ++r) {
            float x0 = acc[t][0][r], x1 = acc[t][1][r];
            float s = x0 + x1, ss = x0 * x0 + x1 * x1;
            #pragma unroll
            for (int mm = 1; mm <= 8; mm <<= 1) { s += __shfl_xor(s, mm); ss += __shfl_xor(ss, mm); }
            float mu = s * (1.f / 32.f);
            float var = ss * (1.f / 32.f) - mu * mu;
            float rs = rsqrtf(var + 1e-6f);
            int vv = i0 + t * 16 + q * 4 + r;
            if (vv < NV) {
                float y0 = (x0 - mu) * rs * gv0 + bv0;
                float y1 = (x1 - mu) * rs * gv1 + bv1;
                hbuf[(size_t)vv * 32 + n]      = rb_f2bf(fmaxf(y0, 0.f));
                hbuf[(size_t)vv * 32 + n + 16] = rb_f2bf(fmaxf(y1, 0.f));
            }
        }
    }
}

extern "C" void kernel_launch(void* const* d_in, const int* in_sizes, int n_in,
                              void* d_out, int out_size, void* d_ws, size_t ws_size,
                              hipStream_t stream)
{
    // setup_inputs() dict order: x, nbr, W1, g1, b1, W2, g2, b2 — all f32 except nbr
    const float* x   = (const float*)d_in[0];
    const int*   nbr = (const int*)d_in[1];
    const float* W1  = (const float*)d_in[2];
    const float* g1  = (const float*)d_in[3];
    const float* b1  = (const float*)d_in[4];
    const float* W2  = (const float*)d_in[5];
    const float* g2  = (const float*)d_in[6];
    const float* b2  = (const float*)d_in[7];
    float* out = (float*)d_out;

    unsigned short* h  = (unsigned short*)d_ws;              // 25.6 MB
    unsigned short* xb = h + (size_t)NV * 32;                // +25.6 MB
    const bool have_xb = ws_size >= (size_t)NV * 32 * 2 * 2; // 51.2 MB needed

    const int nblk = (NV + 511) / 512;   // 782 blocks x 8 waves x 64 voxels

    if (have_xb) {
        // pass 0: xb = bf16(x)
        xcvt_kernel<<<3125, 512, 0, stream>>>(x, xb);
        // pass 1: h = relu(LN(conv1(xb)))
        ResidualBlock_37452114821416_kernel<false><<<nblk, 512, 0, stream>>>(
            x, nbr, W1, g1, b1, out, h, xb);
    } else {
        pass1_f32_kernel<<<nblk, 512, 0, stream>>>(x, nbr, W1, g1, b1, h);
    }
    // pass 2: out = relu(LN(conv2(h)) + x)
    ResidualBlock_37452114821416_kernel<true><<<nblk, 512, 0, stream>>>(
        x, nbr, W2, g2, b2, out, h, h);

    (void)in_sizes; (void)n_in; (void)out_size;
}